// Round 1
// baseline (493.898 us; speedup 1.0000x reference)
//
#include <hip/hip_runtime.h>

#define N_NODES 50000
#define N_EDGES 1600000
#define HEADS 4
#define DPH 16
#define F_IN 128
#define HD 64   // HEADS * DPH

// ---------------------------------------------------------------------------
// Kernel 1: fused QKV projection.
// Each block (192 threads = 3 waves) handles 8 nodes. Wave m (0/1/2) computes
// the Q/K/V projection for its 64 output columns; the 8 node rows are staged
// in LDS so W columns are read once per 8 nodes (coalesced across lanes).
// ---------------------------------------------------------------------------
__global__ void qkv_proj(const float* __restrict__ x,
                         const float* __restrict__ Wq,
                         const float* __restrict__ Wk,
                         const float* __restrict__ Wv,
                         float* __restrict__ Q,
                         float* __restrict__ K,
                         float* __restrict__ V) {
    __shared__ float xs[8][F_IN];
    const int node0 = blockIdx.x * 8;
    const int tid = threadIdx.x;

    for (int i = tid; i < 8 * F_IN; i += 192) {
        const int n = node0 + (i >> 7);
        xs[i >> 7][i & 127] = (n < N_NODES) ? x[(long)n * F_IN + (i & 127)] : 0.f;
    }
    __syncthreads();

    const int m = tid / 64;       // 0=Q, 1=K, 2=V
    const int col = tid & 63;
    const float* W = (m == 0) ? Wq : (m == 1) ? Wk : Wv;
    float* O = (m == 0) ? Q : (m == 1) ? K : V;

    float acc[8] = {0.f, 0.f, 0.f, 0.f, 0.f, 0.f, 0.f, 0.f};
    for (int k = 0; k < F_IN; ++k) {
        const float w = W[k * HD + col];   // coalesced across col lanes
        #pragma unroll
        for (int i = 0; i < 8; ++i) acc[i] += xs[i][k] * w;  // LDS broadcast
    }
    #pragma unroll
    for (int i = 0; i < 8; ++i) {
        const int n = node0 + i;
        if (n < N_NODES) O[n * HD + col] = acc[i];
    }
}

// ---------------------------------------------------------------------------
// Kernel 2: edge attention. One 64-lane wave per edge; lane = h*16 + d.
// Per-head dot via 16-lane shfl_xor butterfly, clamped exp, then atomic
// scatter of score*V into wV (=d_out) and score into z.
// ---------------------------------------------------------------------------
__global__ void edge_attn(const int* __restrict__ src,
                          const int* __restrict__ dst,
                          const float* __restrict__ Q,
                          const float* __restrict__ K,
                          const float* __restrict__ V,
                          float* __restrict__ wV,
                          float* __restrict__ z) {
    const int e = blockIdx.x * 4 + (threadIdx.x >> 6);
    if (e >= N_EDGES) return;
    const int lane = threadIdx.x & 63;

    const int s = src[e];
    const int d = dst[e];

    const float q = Q[d * HD + lane];
    const float k = K[s * HD + lane];
    float p = q * k;
    // reduce over the 16 lanes of this head
    p += __shfl_xor(p, 1, 16);
    p += __shfl_xor(p, 2, 16);
    p += __shfl_xor(p, 4, 16);
    p += __shfl_xor(p, 8, 16);

    const float sc = expf(fminf(fmaxf(p * 0.25f, -5.0f), 5.0f));

    const float v = V[s * HD + lane];
    atomicAdd(&wV[d * HD + lane], sc * v);
    if ((lane & 15) == 0) atomicAdd(&z[d * HEADS + (lane >> 4)], sc);
}

// ---------------------------------------------------------------------------
// Kernel 3: out = wV / (z + 1e-6), in place on d_out.
// ---------------------------------------------------------------------------
__global__ void norm_out(float* __restrict__ out, const float* __restrict__ z) {
    const int i = blockIdx.x * 256 + threadIdx.x;
    if (i >= N_NODES * HD) return;
    const int n = i >> 6;
    const int h = (i >> 4) & 3;
    out[i] = out[i] / (z[n * HEADS + h] + 1e-6f);
}

extern "C" void kernel_launch(void* const* d_in, const int* in_sizes, int n_in,
                              void* d_out, int out_size, void* d_ws, size_t ws_size,
                              hipStream_t stream) {
    const float* x   = (const float*)d_in[0];
    const int*   src = (const int*)d_in[1];
    const int*   dst = (const int*)d_in[2];
    const float* Wq  = (const float*)d_in[3];
    const float* Wk  = (const float*)d_in[4];
    const float* Wv  = (const float*)d_in[5];
    float* out = (float*)d_out;

    float* Q = (float*)d_ws;
    float* K = Q + (size_t)N_NODES * HD;
    float* V = K + (size_t)N_NODES * HD;
    float* z = V + (size_t)N_NODES * HD;

    // accumulators must be zeroed every launch (harness does not re-poison)
    hipMemsetAsync(out, 0, (size_t)N_NODES * HD * sizeof(float), stream);
    hipMemsetAsync(z, 0, (size_t)N_NODES * HEADS * sizeof(float), stream);

    qkv_proj<<<(N_NODES + 7) / 8, 192, 0, stream>>>(x, Wq, Wk, Wv, Q, K, V);
    edge_attn<<<(N_EDGES + 3) / 4, 256, 0, stream>>>(src, dst, Q, K, V, out, z);
    norm_out<<<(N_NODES * HD + 255) / 256, 256, 0, stream>>>(out, z);
}

// Round 2
// 419.071 us; speedup vs baseline: 1.1786x; 1.1786x over previous
//
#include <hip/hip_runtime.h>

#define N_NODES 50000
#define N_EDGES 1600000
#define HEADS 4
#define DPH 16
#define F_IN 128
#define HD 64   // HEADS * DPH

// ---------------------------------------------------------------------------
// Kernel 1: fused QKV projection (unchanged from round 0).
// ---------------------------------------------------------------------------
__global__ void qkv_proj(const float* __restrict__ x,
                         const float* __restrict__ Wq,
                         const float* __restrict__ Wk,
                         const float* __restrict__ Wv,
                         float* __restrict__ Q,
                         float* __restrict__ K,
                         float* __restrict__ V) {
    __shared__ float xs[8][F_IN];
    const int node0 = blockIdx.x * 8;
    const int tid = threadIdx.x;

    for (int i = tid; i < 8 * F_IN; i += 192) {
        const int n = node0 + (i >> 7);
        xs[i >> 7][i & 127] = (n < N_NODES) ? x[(long)n * F_IN + (i & 127)] : 0.f;
    }
    __syncthreads();

    const int m = tid / 64;       // 0=Q, 1=K, 2=V
    const int col = tid & 63;
    const float* W = (m == 0) ? Wq : (m == 1) ? Wk : Wv;
    float* O = (m == 0) ? Q : (m == 1) ? K : V;

    float acc[8] = {0.f, 0.f, 0.f, 0.f, 0.f, 0.f, 0.f, 0.f};
    for (int k = 0; k < F_IN; ++k) {
        const float w = W[k * HD + col];
        #pragma unroll
        for (int i = 0; i < 8; ++i) acc[i] += xs[i][k] * w;
    }
    #pragma unroll
    for (int i = 0; i < 8; ++i) {
        const int n = node0 + i;
        if (n < N_NODES) O[n * HD + col] = acc[i];
    }
}

// ---------------------------------------------------------------------------
// CSR build: histogram of dst, exclusive scan, scatter of src ids.
// ---------------------------------------------------------------------------
__global__ void hist_dst(const int* __restrict__ dst, int* __restrict__ cnt) {
    for (int i = blockIdx.x * blockDim.x + threadIdx.x; i < N_EDGES;
         i += gridDim.x * blockDim.x)
        atomicAdd(&cnt[dst[i]], 1);
}

// single block, 1024 threads; wave-shfl scan + cross-wave LDS scan
__global__ void scan_counts(const int* __restrict__ cnt,
                            int* __restrict__ off, int* __restrict__ cursor) {
    __shared__ int wsum[16];
    __shared__ int carry_s;
    const int tid = threadIdx.x;
    const int lane = tid & 63;
    const int w = tid >> 6;
    if (tid == 0) carry_s = 0;
    __syncthreads();
    for (int base = 0; base < N_NODES; base += 1024) {
        const int i = base + tid;
        const int v = (i < N_NODES) ? cnt[i] : 0;
        int incl = v;
        #pragma unroll
        for (int s = 1; s < 64; s <<= 1) {
            const int t = __shfl_up(incl, s, 64);
            if (lane >= s) incl += t;
        }
        if (lane == 63) wsum[w] = incl;
        __syncthreads();
        if (w == 0) {
            int ws = (lane < 16) ? wsum[lane] : 0;
            #pragma unroll
            for (int s = 1; s < 16; s <<= 1) {
                const int t = __shfl_up(ws, s, 64);
                if (lane >= s) ws += t;
            }
            if (lane < 16) wsum[lane] = ws;
        }
        __syncthreads();
        const int c = carry_s;
        const int wbase = (w == 0) ? 0 : wsum[w - 1];
        const int excl = c + wbase + incl - v;
        if (i < N_NODES) { off[i] = excl; cursor[i] = excl; }
        __syncthreads();
        if (tid == 1023) carry_s = c + wsum[15];
        __syncthreads();
    }
    if (tid == 0) off[N_NODES] = carry_s;
}

__global__ void build_csr(const int* __restrict__ src, const int* __restrict__ dst,
                          int* __restrict__ cursor, int* __restrict__ esrc) {
    for (int i = blockIdx.x * blockDim.x + threadIdx.x; i < N_EDGES;
         i += gridDim.x * blockDim.x) {
        const int pos = atomicAdd(&cursor[dst[i]], 1);
        esrc[pos] = src[i];
    }
}

// ---------------------------------------------------------------------------
// Pull-mode gather: one wave per dst node, accumulate in registers, no atomics.
// lane = h*16 + d. Edge ids batched 64-wide and broadcast via shfl.
// ---------------------------------------------------------------------------
__global__ void node_gather(const int* __restrict__ off,
                            const int* __restrict__ esrc,
                            const float* __restrict__ Q,
                            const float* __restrict__ K,
                            const float* __restrict__ V,
                            float* __restrict__ out) {
    const int n = blockIdx.x * 4 + (threadIdx.x >> 6);
    if (n >= N_NODES) return;
    const int lane = threadIdx.x & 63;
    const int beg = off[n];
    const int end = off[n + 1];
    const float q = Q[n * HD + lane];
    float acc = 0.f, zacc = 0.f;

    for (int base = beg; base < end; base += 64) {
        const int m = (end - base < 64) ? (end - base) : 64;
        const int idx = base + lane;
        const int s_my = (idx < end) ? esrc[idx] : 0;
        int t = 0;
        for (; t + 1 < m; t += 2) {
            const int s0 = __shfl(s_my, t, 64);
            const int s1 = __shfl(s_my, t + 1, 64);
            const float k0 = K[s0 * HD + lane];
            const float v0 = V[s0 * HD + lane];
            const float k1 = K[s1 * HD + lane];
            const float v1 = V[s1 * HD + lane];
            float p0 = q * k0;
            float p1 = q * k1;
            p0 += __shfl_xor(p0, 1, 16);  p1 += __shfl_xor(p1, 1, 16);
            p0 += __shfl_xor(p0, 2, 16);  p1 += __shfl_xor(p1, 2, 16);
            p0 += __shfl_xor(p0, 4, 16);  p1 += __shfl_xor(p1, 4, 16);
            p0 += __shfl_xor(p0, 8, 16);  p1 += __shfl_xor(p1, 8, 16);
            const float sc0 = __expf(fminf(fmaxf(p0 * 0.25f, -5.f), 5.f));
            const float sc1 = __expf(fminf(fmaxf(p1 * 0.25f, -5.f), 5.f));
            acc = fmaf(sc0, v0, acc);
            acc = fmaf(sc1, v1, acc);
            zacc += sc0 + sc1;
        }
        if (t < m) {
            const int s0 = __shfl(s_my, t, 64);
            const float k0 = K[s0 * HD + lane];
            const float v0 = V[s0 * HD + lane];
            float p0 = q * k0;
            p0 += __shfl_xor(p0, 1, 16);
            p0 += __shfl_xor(p0, 2, 16);
            p0 += __shfl_xor(p0, 4, 16);
            p0 += __shfl_xor(p0, 8, 16);
            const float sc0 = __expf(fminf(fmaxf(p0 * 0.25f, -5.f), 5.f));
            acc = fmaf(sc0, v0, acc);
            zacc += sc0;
        }
    }
    out[n * HD + lane] = acc / (zacc + 1e-6f);
}

extern "C" void kernel_launch(void* const* d_in, const int* in_sizes, int n_in,
                              void* d_out, int out_size, void* d_ws, size_t ws_size,
                              hipStream_t stream) {
    const float* x   = (const float*)d_in[0];
    const int*   src = (const int*)d_in[1];
    const int*   dst = (const int*)d_in[2];
    const float* Wq  = (const float*)d_in[3];
    const float* Wk  = (const float*)d_in[4];
    const float* Wv  = (const float*)d_in[5];
    float* out = (float*)d_out;

    float* Q = (float*)d_ws;
    float* K = Q + (size_t)N_NODES * HD;
    float* V = K + (size_t)N_NODES * HD;
    int* cnt    = (int*)(V + (size_t)N_NODES * HD);
    int* off    = cnt + N_NODES;
    int* cursor = off + N_NODES + 1;
    int* esrc   = cursor + N_NODES;

    hipMemsetAsync(cnt, 0, (size_t)N_NODES * sizeof(int), stream);

    qkv_proj<<<(N_NODES + 7) / 8, 192, 0, stream>>>(x, Wq, Wk, Wv, Q, K, V);
    hist_dst<<<2048, 256, 0, stream>>>(dst, cnt);
    scan_counts<<<1, 1024, 0, stream>>>(cnt, off, cursor);
    build_csr<<<2048, 256, 0, stream>>>(src, dst, cursor, esrc);
    node_gather<<<(N_NODES + 3) / 4, 256, 0, stream>>>(off, esrc, Q, K, V, out);
}

// Round 3
// 333.583 us; speedup vs baseline: 1.4806x; 1.2563x over previous
//
#include <hip/hip_runtime.h>

#define N_NODES 50000
#define N_EDGES 1600000
#define HEADS 4
#define DPH 16
#define F_IN 128
#define HD 64   // HEADS * DPH

// ---------------------------------------------------------------------------
// Kernel 1: fused QKV projection (unchanged).
// ---------------------------------------------------------------------------
__global__ void qkv_proj(const float* __restrict__ x,
                         const float* __restrict__ Wq,
                         const float* __restrict__ Wk,
                         const float* __restrict__ Wv,
                         float* __restrict__ Q,
                         float* __restrict__ K,
                         float* __restrict__ V) {
    __shared__ float xs[8][F_IN];
    const int node0 = blockIdx.x * 8;
    const int tid = threadIdx.x;

    for (int i = tid; i < 8 * F_IN; i += 192) {
        const int n = node0 + (i >> 7);
        xs[i >> 7][i & 127] = (n < N_NODES) ? x[(long)n * F_IN + (i & 127)] : 0.f;
    }
    __syncthreads();

    const int m = tid / 64;       // 0=Q, 1=K, 2=V
    const int col = tid & 63;
    const float* W = (m == 0) ? Wq : (m == 1) ? Wk : Wv;
    float* O = (m == 0) ? Q : (m == 1) ? K : V;

    float acc[8] = {0.f, 0.f, 0.f, 0.f, 0.f, 0.f, 0.f, 0.f};
    for (int k = 0; k < F_IN; ++k) {
        const float w = W[k * HD + col];
        #pragma unroll
        for (int i = 0; i < 8; ++i) acc[i] += xs[i][k] * w;
    }
    #pragma unroll
    for (int i = 0; i < 8; ++i) {
        const int n = node0 + i;
        if (n < N_NODES) O[n * HD + col] = acc[i];
    }
}

// ---------------------------------------------------------------------------
// Kernel 2: per-dst linked list. next[] write is fully coalesced; the
// atomicExch on head[] writes through at 4B granularity (no line
// amplification, unlike the CSR esrc scatter).
// ---------------------------------------------------------------------------
__global__ void build_links(const int* __restrict__ dst,
                            int* __restrict__ head,
                            int* __restrict__ next) {
    for (int i = blockIdx.x * blockDim.x + threadIdx.x; i < N_EDGES;
         i += gridDim.x * blockDim.x) {
        next[i] = atomicExch(&head[dst[i]], i);
    }
}

// ---------------------------------------------------------------------------
// Kernel 3: pull-mode gather, one wave per dst node, register accumulation,
// no atomics. Walks the node's edge list; next[e] is issued first so the
// pointer-chase latency overlaps the K/V math; 8 waves/SIMD hide the rest.
// lane = h*16 + d.
// ---------------------------------------------------------------------------
__global__ void node_gather(const int* __restrict__ head,
                            const int* __restrict__ next,
                            const int* __restrict__ src,
                            const float* __restrict__ Q,
                            const float* __restrict__ K,
                            const float* __restrict__ V,
                            float* __restrict__ out) {
    const int n = blockIdx.x * 4 + (threadIdx.x >> 6);
    if (n >= N_NODES) return;
    const int lane = threadIdx.x & 63;
    const float q = Q[n * HD + lane];

    float acc = 0.f, zacc = 0.f;
    int e = head[n];
    while (e >= 0) {
        const int en = next[e];          // issue dependent load early
        const int s  = src[e];           // broadcast load (uniform addr)
        const float k = K[s * HD + lane];
        const float v = V[s * HD + lane];
        float p = q * k;
        p += __shfl_xor(p, 1, 16);
        p += __shfl_xor(p, 2, 16);
        p += __shfl_xor(p, 4, 16);
        p += __shfl_xor(p, 8, 16);
        const float sc = __expf(fminf(fmaxf(p * 0.25f, -5.f), 5.f));
        acc = fmaf(sc, v, acc);
        zacc += sc;
        e = en;
    }
    out[n * HD + lane] = acc / (zacc + 1e-6f);
}

extern "C" void kernel_launch(void* const* d_in, const int* in_sizes, int n_in,
                              void* d_out, int out_size, void* d_ws, size_t ws_size,
                              hipStream_t stream) {
    const float* x   = (const float*)d_in[0];
    const int*   src = (const int*)d_in[1];
    const int*   dst = (const int*)d_in[2];
    const float* Wq  = (const float*)d_in[3];
    const float* Wk  = (const float*)d_in[4];
    const float* Wv  = (const float*)d_in[5];
    float* out = (float*)d_out;

    float* Q = (float*)d_ws;
    float* K = Q + (size_t)N_NODES * HD;
    float* V = K + (size_t)N_NODES * HD;
    int* head = (int*)(V + (size_t)N_NODES * HD);
    int* next = head + N_NODES;

    // head = -1 everywhere (0xFF bytes)
    hipMemsetAsync(head, 0xFF, (size_t)N_NODES * sizeof(int), stream);

    qkv_proj<<<(N_NODES + 7) / 8, 192, 0, stream>>>(x, Wq, Wk, Wv, Q, K, V);
    build_links<<<2048, 256, 0, stream>>>(dst, head, next);
    node_gather<<<(N_NODES + 3) / 4, 256, 0, stream>>>(head, next, src, Q, K, V, out);
}